// Round 11
// baseline (360.526 us; speedup 1.0000x reference)
//
#include <hip/hip_runtime.h>
#include <hip/hip_bf16.h>

#define H 1024
#define B 32
#define S 2048

typedef __attribute__((ext_vector_type(8))) _Float16 h8;
typedef __attribute__((ext_vector_type(4))) _Float16 h4;
typedef __attribute__((ext_vector_type(4))) float f32x4;

__device__ __forceinline__ float fast_tanh(float x) {
    float a = __builtin_fabsf(x);
    float e = __expf(2.0f * a);
    float r = 1.0f - 2.0f / (e + 1.0f);   // == tanh(a)
    return __builtin_copysignf(r, x);
}

__device__ __forceinline__ void gload_lds16(const void* g, void* l) {
    __builtin_amdgcn_global_load_lds(
        (const __attribute__((address_space(1))) unsigned int*)g,
        (__attribute__((address_space(3))) unsigned int*)l, 16, 0, 0);
}

__device__ __forceinline__ h8 cvt8f(float4 a, float4 b) {
    return (h8){(_Float16)a.x, (_Float16)a.y, (_Float16)a.z, (_Float16)a.w,
                (_Float16)b.x, (_Float16)b.y, (_Float16)b.z, (_Float16)b.w};
}

// ---------------- proj_h = h @ Wh^T + b_attn  (32 x 1024) ----------------
__global__ __launch_bounds__(256) void proj_h_kernel(
    const float* __restrict__ hidden, const float* __restrict__ W,
    const float* __restrict__ b_attn, float* __restrict__ ph)
{
    const int b = blockIdx.y;
    const int tid = threadIdx.x;
    __shared__ float hs[H];
    const float4* hr = (const float4*)(hidden + (size_t)(B + b) * H); // hidden[-1]
    ((float4*)hs)[tid] = hr[tid];
    __syncthreads();
    const int w = tid >> 6, lane = tid & 63;
    const int o = blockIdx.x * 4 + w;
    const float* wr = W + (size_t)o * (2 * H);
    float acc = 0.f;
    #pragma unroll
    for (int i = 0; i < 16; ++i) {
        const int k = i * 64 + lane;
        acc += wr[k] * hs[k];
    }
    #pragma unroll
    for (int off = 32; off; off >>= 1) acc += __shfl_xor(acc, off);
    if (lane == 0) ph[b * H + o] = acc + b_attn[o];
}

// ---------------- We (f32) -> We_h (fp16), row-major [1024][1024] --------
__global__ __launch_bounds__(256) void conv_We(
    const float* __restrict__ W, _Float16* __restrict__ We_h)
{
    const int o = blockIdx.x;
    const int t = threadIdx.x;
    float4 f = *(const float4*)(W + (size_t)o * 2048 + 1024 + t * 4);
    h4 hv = {(_Float16)f.x, (_Float16)f.y, (_Float16)f.z, (_Float16)f.w};
    *(h4*)(We_h + (size_t)o * 1024 + t * 4) = hv;
}

// ------- score GEMM v13: 128x128, BK=64, dbuf fp16, 1 barrier/iter ------
// Grid 4096 = 512(M) x 8(N), XCD-swizzled. Per iter: issue A-loads(t+1) +
// B-DMA(t+1) early -> compute(t) (~900cyc covers DMA) -> cvt+WRITE_A(t+1)
// -> one __syncthreads. All swizzles are measured-0-conflict patterns:
// A,B fp16 [128][64] rows 128B = 8 slots, slot^(row&7) (v4/v5 proven).
__global__ __launch_bounds__(256, 2) void score_v13(
    const float* __restrict__ enc, const _Float16* __restrict__ We_h,
    const float* __restrict__ ph, const float* __restrict__ v,
    float* __restrict__ partial)
{
    __shared__ _Float16 Als[2][128][64];   // 2 x 16 KB
    __shared__ _Float16 Bls[2][128][64];   // 2 x 16 KB
    __shared__ float slds[256];

    const int tid = threadIdx.x;
    const int bid = blockIdx.x;
    const int x  = bid & 7;
    const int ii = bid >> 3;
    const int nb = ii & 7;
    const int mt = (ii >> 3) * 8 + x;      // 0..511
    const int b  = mt >> 4;

    const int lane = tid & 63;
    const int wid  = tid >> 6;
    const int wm = wid >> 1, wn = wid & 1;
    const int l15 = lane & 15, lg = lane >> 4;

    // A reg-stage map (v4-proven): 8 threads/row, 8 slots
    const int arow = tid >> 3, aslot = tid & 7;
    // B DMA map (v5-proven)
    const int b_r = lane >> 3, b_s = lane & 7;
    const float*    Ag = enc  + (size_t)(mt * 128) * H;
    const _Float16* Bg = We_h + (size_t)(nb * 128) * H;

    #define STAGE_B(buf, k0) { \
        _Pragma("unroll") \
        for (int q = 0; q < 4; ++q) { \
            const int n = q * 32 + wid * 8 + b_r; \
            gload_lds16(Bg + (size_t)n * H + (k0) + ((b_s ^ (n & 7)) * 8), \
                        (char*)&Bls[buf][0][0] + (q * 32 + wid * 8) * 128); \
        } }
    #define LOAD_A(k0, f) { \
        _Pragma("unroll") \
        for (int p = 0; p < 4; ++p) { \
            const float* src = Ag + (size_t)(p * 32 + arow) * H + (k0) + aslot * 8; \
            f[2 * p]     = *(const float4*)src; \
            f[2 * p + 1] = *(const float4*)(src + 4); \
        } }
    #define WRITE_A(buf, f) { \
        _Pragma("unroll") \
        for (int p = 0; p < 4; ++p) { \
            const int m = p * 32 + arow; \
            *(h8*)((char*)&Als[buf][0][0] + m * 128 + ((aslot ^ (m & 7)) * 16)) = \
                cvt8f(f[2 * p], f[2 * p + 1]); \
        } }

    f32x4 acc[4][4];
    #pragma unroll
    for (int mi = 0; mi < 4; ++mi)
        #pragma unroll
        for (int ni = 0; ni < 4; ++ni) acc[mi][ni] = (f32x4){0.f, 0.f, 0.f, 0.f};

    // ---- prologue: stage tile 0 (latency exposed once) ----
    float4 fa[8];
    LOAD_A(0, fa)
    STAGE_B(0, 0)
    WRITE_A(0, fa)
    __syncthreads();

    for (int t = 0; t < 16; ++t) {
        const int cur = t & 1, nxt = cur ^ 1;
        if (t < 15) {
            LOAD_A((t + 1) * 64, fa)     // issue early: lands under compute
            STAGE_B(nxt, (t + 1) * 64)   // DMA early: drained at barrier, covered
        }
        // compute tile cur
        #pragma unroll
        for (int ks = 0; ks < 2; ++ks) {
            h8 af[4], bf[4];
            const int sl = ks * 4 + lg;
            #pragma unroll
            for (int mi = 0; mi < 4; ++mi) {
                const int r = wm * 64 + mi * 16 + l15;
                af[mi] = *(const h8*)((const char*)&Als[cur][0][0] + r * 128 +
                                      ((sl ^ (r & 7)) * 16));
            }
            #pragma unroll
            for (int ni = 0; ni < 4; ++ni) {
                const int n = wn * 64 + ni * 16 + l15;
                bf[ni] = *(const h8*)((const char*)&Bls[cur][0][0] + n * 128 +
                                      ((sl ^ (n & 7)) * 16));
            }
            #pragma unroll
            for (int mi = 0; mi < 4; ++mi)
                #pragma unroll
                for (int ni = 0; ni < 4; ++ni)
                    acc[mi][ni] = __builtin_amdgcn_mfma_f32_16x16x32_f16(
                        af[mi], bf[ni], acc[mi][ni], 0, 0, 0);
        }
        if (t < 15) WRITE_A(nxt, fa)     // A regs arrived during compute
        __syncthreads();                 // drains lgkm + (already-landed) DMA
    }
    #undef STAGE_B
    #undef LOAD_A
    #undef WRITE_A

    // ---- epilogue: tanh + v-dot over this block's 128 cols ----
    float vreg[4], preg[4];
    #pragma unroll
    for (int ni = 0; ni < 4; ++ni) {
        const int gcol = nb * 128 + wn * 64 + ni * 16 + l15;
        vreg[ni] = v[gcol];
        preg[ni] = ph[b * H + gcol];
    }
    #pragma unroll
    for (int mi = 0; mi < 4; ++mi) {
        #pragma unroll
        for (int j = 0; j < 4; ++j) {
            float p = 0.f;
            #pragma unroll
            for (int ni = 0; ni < 4; ++ni)
                p += vreg[ni] * fast_tanh(acc[mi][ni][j] + preg[ni]);
            p += __shfl_xor(p, 1); p += __shfl_xor(p, 2);
            p += __shfl_xor(p, 4); p += __shfl_xor(p, 8);
            if (l15 == 0)
                slds[wn * 128 + wm * 64 + mi * 16 + lg * 4 + j] = p;
        }
    }
    __syncthreads();
    if (tid < 128)
        partial[(size_t)nb * (B * S) + mt * 128 + tid] = slds[tid] + slds[128 + tid];
}

// ---- fallback score (R4 path, B reg-staged from f32 W; only if ws tiny) ----
__global__ __launch_bounds__(256) void score_v4f(
    const float* __restrict__ enc, const float* __restrict__ Wf,
    const float* __restrict__ ph, const float* __restrict__ v,
    float* __restrict__ partial)
{
    __shared__ _Float16 As[128 * 64];
    __shared__ _Float16 Bs[128 * 64];
    __shared__ float slds[256];
    const int tid = threadIdx.x;
    const int bid = blockIdx.x;
    const int x  = bid & 7;
    const int ii = bid >> 3;
    const int nb = ii & 7;
    const int mt = (ii >> 3) * 8 + x;
    const int b  = mt >> 4;
    const int lane = tid & 63;
    const int wid  = tid >> 6;
    const int wm = wid >> 1, wn = wid & 1;
    const int l15 = lane & 15, lg = lane >> 4;
    const int arow  = tid >> 3;
    const int aslot = tid & 7;
    f32x4 acc[4][4];
    #pragma unroll
    for (int mi = 0; mi < 4; ++mi)
        #pragma unroll
        for (int ni = 0; ni < 4; ++ni) acc[mi][ni] = (f32x4){0.f, 0.f, 0.f, 0.f};
    for (int kt = 0; kt < 16; ++kt) {
        const int k0 = kt * 64;
        __syncthreads();
        #pragma unroll
        for (int p = 0; p < 4; ++p) {
            const int m = p * 32 + arow;
            const float* src = enc + (size_t)(mt * 128 + m) * H + k0 + aslot * 8;
            float4 f0 = *(const float4*)src;
            float4 f1 = *(const float4*)(src + 4);
            *(h8*)((char*)As + m * 128 + ((aslot ^ (m & 7)) * 16)) = cvt8f(f0, f1);
        }
        #pragma unroll
        for (int p = 0; p < 4; ++p) {
            const int n  = p * 32 + arow;
            const int gn = nb * 128 + n;
            const float* src = Wf + (size_t)gn * 2048 + 1024 + k0 + aslot * 8;
            float4 f0 = *(const float4*)src;
            float4 f1 = *(const float4*)(src + 4);
            *(h8*)((char*)Bs + n * 128 + ((aslot ^ (n & 7)) * 16)) = cvt8f(f0, f1);
        }
        __syncthreads();
        #pragma unroll
        for (int ks = 0; ks < 2; ++ks) {
            h8 ah[4], bh[4];
            const int sl = ks * 4 + lg;
            #pragma unroll
            for (int mi = 0; mi < 4; ++mi) {
                const int r = wm * 64 + mi * 16 + l15;
                ah[mi] = *(const h8*)((char*)As + r * 128 + 16 * (sl ^ (r & 7)));
            }
            #pragma unroll
            for (int ni = 0; ni < 4; ++ni) {
                const int r = wn * 64 + ni * 16 + l15;
                bh[ni] = *(const h8*)((char*)Bs + r * 128 + 16 * (sl ^ (r & 7)));
            }
            #pragma unroll
            for (int mi = 0; mi < 4; ++mi)
                #pragma unroll
                for (int ni = 0; ni < 4; ++ni)
                    acc[mi][ni] = __builtin_amdgcn_mfma_f32_16x16x32_f16(
                        ah[mi], bh[ni], acc[mi][ni], 0, 0, 0);
        }
    }
    float vreg[4], preg[4];
    #pragma unroll
    for (int ni = 0; ni < 4; ++ni) {
        const int gcol = nb * 128 + wn * 64 + ni * 16 + l15;
        vreg[ni] = v[gcol];
        preg[ni] = ph[b * H + gcol];
    }
    #pragma unroll
    for (int mi = 0; mi < 4; ++mi) {
        #pragma unroll
        for (int j = 0; j < 4; ++j) {
            float p = 0.f;
            #pragma unroll
            for (int ni = 0; ni < 4; ++ni)
                p += vreg[ni] * fast_tanh(acc[mi][ni][j] + preg[ni]);
            p += __shfl_xor(p, 1); p += __shfl_xor(p, 2);
            p += __shfl_xor(p, 4); p += __shfl_xor(p, 8);
            if (l15 == 0)
                slds[wn * 128 + wm * 64 + mi * 16 + lg * 4 + j] = p;
        }
    }
    __syncthreads();
    if (tid < 128)
        partial[(size_t)nb * (B * S) + mt * 128 + tid] = slds[tid] + slds[128 + tid];
}

// ---------------- softmax over S per batch (sums nparts N-partials) ------
__global__ __launch_bounds__(256) void softmax_kernel(
    const float* __restrict__ partial, float* __restrict__ attn, int nparts)
{
    const int b = blockIdx.x, tid = threadIdx.x;
    float xv[8];
    float m = -1e30f;
    #pragma unroll
    for (int i = 0; i < 8; ++i) {
        float s = 0.f;
        for (int nb = 0; nb < nparts; ++nb)
            s += partial[(size_t)nb * (B * S) + b * S + tid + i * 256];
        xv[i] = s;
        m = fmaxf(m, s);
    }
    #pragma unroll
    for (int off = 32; off; off >>= 1) m = fmaxf(m, __shfl_xor(m, off));
    __shared__ float wred[4], wsum[4];
    const int w = tid >> 6;
    if ((tid & 63) == 0) wred[w] = m;
    __syncthreads();
    const float M = fmaxf(fmaxf(wred[0], wred[1]), fmaxf(wred[2], wred[3]));
    float s = 0.f;
    #pragma unroll
    for (int i = 0; i < 8; ++i) { xv[i] = expf(xv[i] - M); s += xv[i]; }
    #pragma unroll
    for (int off = 32; off; off >>= 1) s += __shfl_xor(s, off);
    if ((tid & 63) == 0) wsum[w] = s;
    __syncthreads();
    const float inv = 1.f / (wsum[0] + wsum[1] + wsum[2] + wsum[3]);
    #pragma unroll
    for (int i = 0; i < 8; ++i) attn[b * S + tid + i * 256] = xv[i] * inv;
}

// ---------------- context: partial over S-chunks, then reduce ------------
__global__ __launch_bounds__(256) void ctx_partial(
    const float* __restrict__ enc, const float* __restrict__ attn,
    float* __restrict__ part, int rows)
{
    const int sc = blockIdx.x;
    const int b  = blockIdx.y;
    const int tid = threadIdx.x;
    const float* encb = enc + ((size_t)b * S + (size_t)sc * rows) * H;
    const float* wb = attn + b * S + sc * rows;
    __shared__ float wl[256];
    if (tid < rows) wl[tid] = wb[tid];
    __syncthreads();
    float4 acc = {0.f, 0.f, 0.f, 0.f};
    for (int s = 0; s < rows; ++s) {
        const float wgt = wl[s];
        const float4 e = *(const float4*)(encb + (size_t)s * H + tid * 4);
        acc.x += wgt * e.x; acc.y += wgt * e.y; acc.z += wgt * e.z; acc.w += wgt * e.w;
    }
    ((float4*)(part + ((size_t)(sc * B + b)) * H))[tid] = acc;
}

__global__ __launch_bounds__(256) void ctx_reduce(
    const float* __restrict__ part, float* __restrict__ ctx, int nch)
{
    const int i = blockIdx.x * 256 + threadIdx.x;
    float s = 0.f;
    for (int c = 0; c < nch; ++c) s += part[(size_t)c * (B * H) + i];
    ctx[i] = s;
}

extern "C" void kernel_launch(void* const* d_in, const int* in_sizes, int n_in,
                              void* d_out, int out_size, void* d_ws, size_t ws_size,
                              hipStream_t stream) {
    const float* hidden = (const float*)d_in[0];
    const float* enc    = (const float*)d_in[1];
    const float* W      = (const float*)d_in[2];
    const float* b_attn = (const float*)d_in[3];
    const float* v      = (const float*)d_in[4];
    float* ctx  = (float*)d_out;               // (B, H)
    float* attn = ctx + B * H;                 // (B, S)
    float* ws      = (float*)d_ws;
    float* region  = ws;                       // 524288 f32: score partials, then ctx part
    float* ph      = ws + 524288;              // 32768 f32
    _Float16* We_h = (_Float16*)(ws + 524288 + 32768);  // 1M halfs

    proj_h_kernel<<<dim3(H / 4, B), 256, 0, stream>>>(hidden, W, b_attn, ph);

    const size_t need_primary = (size_t)(524288 + 32768 + 524288) * 4;
    if (ws_size >= need_primary) {
        conv_We<<<1024, 256, 0, stream>>>(W, We_h);
        score_v13<<<4096, 256, 0, stream>>>(enc, We_h, ph, v, region);
        softmax_kernel<<<dim3(B), 256, 0, stream>>>(region, attn, 8);
    } else {
        score_v4f<<<4096, 256, 0, stream>>>(enc, W, ph, v, region);
        softmax_kernel<<<dim3(B), 256, 0, stream>>>(region, attn, 8);
    }
    ctx_partial<<<dim3(16, B), 256, 0, stream>>>(enc, attn, region, 128);
    ctx_reduce<<<dim3((B * H) / 256), 256, 0, stream>>>(region, ctx, 16);
}

// Round 12
// 247.536 us; speedup vs baseline: 1.4565x; 1.4565x over previous
//
#include <hip/hip_runtime.h>
#include <hip/hip_bf16.h>

#define H 1024
#define B 32
#define S 2048

typedef __attribute__((ext_vector_type(8))) _Float16 h8;
typedef __attribute__((ext_vector_type(4))) _Float16 h4;
typedef __attribute__((ext_vector_type(4))) float f32x4;

__device__ __forceinline__ float fast_tanh(float x) {
    float a = __builtin_fabsf(x);
    float e = __expf(2.0f * a);
    float r = 1.0f - 2.0f / (e + 1.0f);   // == tanh(a)
    return __builtin_copysignf(r, x);
}

__device__ __forceinline__ void gload_lds16(const void* g, void* l) {
    __builtin_amdgcn_global_load_lds(
        (const __attribute__((address_space(1))) unsigned int*)g,
        (__attribute__((address_space(3))) unsigned int*)l, 16, 0, 0);
}

__device__ __forceinline__ h8 cvt8(f32x4 a, f32x4 b) {
    return (h8){(_Float16)a[0], (_Float16)a[1], (_Float16)a[2], (_Float16)a[3],
                (_Float16)b[0], (_Float16)b[1], (_Float16)b[2], (_Float16)b[3]};
}
__device__ __forceinline__ h8 cvt8f(float4 a, float4 b) {
    return (h8){(_Float16)a.x, (_Float16)a.y, (_Float16)a.z, (_Float16)a.w,
                (_Float16)b.x, (_Float16)b.y, (_Float16)b.z, (_Float16)b.w};
}

// ---------------- proj_h = h @ Wh^T + b_attn  (32 x 1024) ----------------
__global__ __launch_bounds__(256) void proj_h_kernel(
    const float* __restrict__ hidden, const float* __restrict__ W,
    const float* __restrict__ b_attn, float* __restrict__ ph)
{
    const int b = blockIdx.y;
    const int tid = threadIdx.x;
    __shared__ float hs[H];
    const float4* hr = (const float4*)(hidden + (size_t)(B + b) * H); // hidden[-1]
    ((float4*)hs)[tid] = hr[tid];
    __syncthreads();
    const int w = tid >> 6, lane = tid & 63;
    const int o = blockIdx.x * 4 + w;
    const float* wr = W + (size_t)o * (2 * H);
    float acc = 0.f;
    #pragma unroll
    for (int i = 0; i < 16; ++i) {
        const int k = i * 64 + lane;
        acc += wr[k] * hs[k];
    }
    #pragma unroll
    for (int off = 32; off; off >>= 1) acc += __shfl_xor(acc, off);
    if (lane == 0) ph[b * H + o] = acc + b_attn[o];
}

// ---------------- We (f32) -> We_h (fp16), row-major [1024][1024] --------
__global__ __launch_bounds__(256) void conv_We(
    const float* __restrict__ W, _Float16* __restrict__ We_h)
{
    const int o = blockIdx.x;
    const int t = threadIdx.x;
    float4 f = *(const float4*)(W + (size_t)o * 2048 + 1024 + t * 4);
    h4 hv = {(_Float16)f.x, (_Float16)f.y, (_Float16)f.z, (_Float16)f.w};
    *(h4*)(We_h + (size_t)o * 1024 + t * 4) = hv;
}

// ------- score GEMM v12 (champion): convoy, tile 128Mx256N, BK=64 -------
// Grid 2048 = 512(M) x 4(N), XCD-chunked. 2-barrier structure; swizzles
// measured 0-conflict. BN=256 keeps staged bytes/MAC at 0.031 (m97 ratio).
__global__ __launch_bounds__(512, 4) void score_v12(
    const float* __restrict__ enc, const _Float16* __restrict__ We_h,
    const float* __restrict__ ph, const float* __restrict__ v,
    float* __restrict__ partial)
{
    __shared__ float    Als[128][64];   // 32 KB (f32, rows 256B, 16 slots)
    __shared__ _Float16 Bls[256][64];   // 32 KB (fp16, rows 128B, 8 slots)
    __shared__ float slds[512];

    const int tid = threadIdx.x;
    const int bid = blockIdx.x;
    const int xcd = bid & 7;
    const int lin = xcd * 256 + (bid >> 3);  // contiguous chunk per XCD
    const int nt = lin & 3, mt = lin >> 2;   // 4 N-blocks of one M-panel adjacent
    const int b  = mt >> 4;

    const int lane = tid & 63;
    const int wid  = tid >> 6;
    const int wm = wid >> 2, wn = wid & 3;   // 2 x 4 wave grid
    const int l15 = lane & 15, lg = lane >> 4;

    // DMA lane maps (dst = wave-uniform base; HW adds lane*16)
    const int a_r = lane >> 4;               // row within 4-row chunk
    const int a_s = lane & 15;               // src 16B slot (of 16)
    const int b_r = lane >> 3;               // row within 8-row chunk
    const int b_s = lane & 7;                // src 16B slot (of 8)
    const float*    Ag = enc  + (size_t)(mt * 128) * H;
    const _Float16* Bg = We_h + (size_t)(nt * 256) * H;

    f32x4 acc[4][4];
    #pragma unroll
    for (int mi = 0; mi < 4; ++mi)
        #pragma unroll
        for (int ni = 0; ni < 4; ++ni) acc[mi][ni] = (f32x4){0.f, 0.f, 0.f, 0.f};

    for (int kt = 0; kt < 16; ++kt) {
        const int k0 = kt * 64;
        __syncthreads();                     // prev compute done -> LDS reusable
        // A tile: 128 rows x 256B = 32 chunks of 4 rows; 4 issues/wave
        #pragma unroll
        for (int q = 0; q < 4; ++q) {
            const int c = q * 8 + wid;       // chunk 0..31
            const int r = c * 4 + a_r;
            gload_lds16(Ag + (size_t)r * H + k0 + ((a_s ^ (r & 15)) * 4),
                        (char*)&Als[0][0] + c * 1024);
        }
        // B tile: 256 rows x 128B = 32 chunks of 8 rows; 4 issues/wave
        #pragma unroll
        for (int q = 0; q < 4; ++q) {
            const int c = q * 8 + wid;
            const int n = c * 8 + b_r;
            gload_lds16(Bg + (size_t)n * H + k0 + ((b_s ^ (n & 7)) * 8),
                        (char*)&Bls[0][0] + c * 1024);
        }
        __syncthreads();                     // drain (covered by co-resident block)

        #pragma unroll
        for (int ks = 0; ks < 2; ++ks) {
            h8 af[4], bf[4];
            #pragma unroll
            for (int mi = 0; mi < 4; ++mi) {
                const int r  = wm * 64 + mi * 16 + l15;
                const int s0 = ks * 8 + lg * 2;
                const char* rowp = (const char*)&Als[r][0];
                f32x4 f0 = *(const f32x4*)(rowp + ((s0       ^ (r & 15)) * 16));
                f32x4 f1 = *(const f32x4*)(rowp + (((s0 + 1) ^ (r & 15)) * 16));
                af[mi] = cvt8(f0, f1);
            }
            #pragma unroll
            for (int ni = 0; ni < 4; ++ni) {
                const int n  = wn * 64 + ni * 16 + l15;
                const int sl = ks * 4 + lg;
                bf[ni] = *(const h8*)((const char*)&Bls[n][0] + ((sl ^ (n & 7)) * 16));
            }
            #pragma unroll
            for (int mi = 0; mi < 4; ++mi)
                #pragma unroll
                for (int ni = 0; ni < 4; ++ni)
                    acc[mi][ni] = __builtin_amdgcn_mfma_f32_16x16x32_f16(
                        af[mi], bf[ni], acc[mi][ni], 0, 0, 0);
        }
    }

    // ---- epilogue: tanh + v-dot over this block's 256 cols ----
    float vreg[4], preg[4];
    #pragma unroll
    for (int ni = 0; ni < 4; ++ni) {
        const int gcol = nt * 256 + wn * 64 + ni * 16 + l15;
        vreg[ni] = v[gcol];
        preg[ni] = ph[b * H + gcol];
    }
    #pragma unroll
    for (int mi = 0; mi < 4; ++mi) {
        #pragma unroll
        for (int j = 0; j < 4; ++j) {
            float p = 0.f;
            #pragma unroll
            for (int ni = 0; ni < 4; ++ni)
                p += vreg[ni] * fast_tanh(acc[mi][ni][j] + preg[ni]);
            p += __shfl_xor(p, 1); p += __shfl_xor(p, 2);
            p += __shfl_xor(p, 4); p += __shfl_xor(p, 8);
            if (l15 == 0)
                slds[wn * 128 + wm * 64 + mi * 16 + lg * 4 + j] = p;
        }
    }
    __syncthreads();
    if (tid < 128)
        partial[(size_t)nt * (B * S) + mt * 128 + tid] =
            slds[tid] + slds[128 + tid] + slds[256 + tid] + slds[384 + tid];
}

// ---- fallback score (R4 path, B reg-staged from f32 W; only if ws tiny) ----
__global__ __launch_bounds__(256) void score_v4f(
    const float* __restrict__ enc, const float* __restrict__ Wf,
    const float* __restrict__ ph, const float* __restrict__ v,
    float* __restrict__ partial)
{
    __shared__ _Float16 As[128 * 64];
    __shared__ _Float16 Bs[128 * 64];
    __shared__ float slds[256];
    const int tid = threadIdx.x;
    const int bid = blockIdx.x;
    const int x  = bid & 7;
    const int ii = bid >> 3;
    const int nb = ii & 7;
    const int mt = (ii >> 3) * 8 + x;
    const int b  = mt >> 4;
    const int lane = tid & 63;
    const int wid  = tid >> 6;
    const int wm = wid >> 1, wn = wid & 1;
    const int l15 = lane & 15, lg = lane >> 4;
    const int arow  = tid >> 3;
    const int aslot = tid & 7;
    f32x4 acc[4][4];
    #pragma unroll
    for (int mi = 0; mi < 4; ++mi)
        #pragma unroll
        for (int ni = 0; ni < 4; ++ni) acc[mi][ni] = (f32x4){0.f, 0.f, 0.f, 0.f};
    for (int kt = 0; kt < 16; ++kt) {
        const int k0 = kt * 64;
        __syncthreads();
        #pragma unroll
        for (int p = 0; p < 4; ++p) {
            const int m = p * 32 + arow;
            const float* src = enc + (size_t)(mt * 128 + m) * H + k0 + aslot * 8;
            float4 f0 = *(const float4*)src;
            float4 f1 = *(const float4*)(src + 4);
            *(h8*)((char*)As + m * 128 + ((aslot ^ (m & 7)) * 16)) = cvt8f(f0, f1);
        }
        #pragma unroll
        for (int p = 0; p < 4; ++p) {
            const int n  = p * 32 + arow;
            const int gn = nb * 128 + n;
            const float* src = Wf + (size_t)gn * 2048 + 1024 + k0 + aslot * 8;
            float4 f0 = *(const float4*)src;
            float4 f1 = *(const float4*)(src + 4);
            *(h8*)((char*)Bs + n * 128 + ((aslot ^ (n & 7)) * 16)) = cvt8f(f0, f1);
        }
        __syncthreads();
        #pragma unroll
        for (int ks = 0; ks < 2; ++ks) {
            h8 ah[4], bh[4];
            const int sl = ks * 4 + lg;
            #pragma unroll
            for (int mi = 0; mi < 4; ++mi) {
                const int r = wm * 64 + mi * 16 + l15;
                ah[mi] = *(const h8*)((char*)As + r * 128 + 16 * (sl ^ (r & 7)));
            }
            #pragma unroll
            for (int ni = 0; ni < 4; ++ni) {
                const int r = wn * 64 + ni * 16 + l15;
                bh[ni] = *(const h8*)((char*)Bs + r * 128 + 16 * (sl ^ (r & 7)));
            }
            #pragma unroll
            for (int mi = 0; mi < 4; ++mi)
                #pragma unroll
                for (int ni = 0; ni < 4; ++ni)
                    acc[mi][ni] = __builtin_amdgcn_mfma_f32_16x16x32_f16(
                        ah[mi], bh[ni], acc[mi][ni], 0, 0, 0);
        }
    }
    float vreg[4], preg[4];
    #pragma unroll
    for (int ni = 0; ni < 4; ++ni) {
        const int gcol = nb * 128 + wn * 64 + ni * 16 + l15;
        vreg[ni] = v[gcol];
        preg[ni] = ph[b * H + gcol];
    }
    #pragma unroll
    for (int mi = 0; mi < 4; ++mi) {
        #pragma unroll
        for (int j = 0; j < 4; ++j) {
            float p = 0.f;
            #pragma unroll
            for (int ni = 0; ni < 4; ++ni)
                p += vreg[ni] * fast_tanh(acc[mi][ni][j] + preg[ni]);
            p += __shfl_xor(p, 1); p += __shfl_xor(p, 2);
            p += __shfl_xor(p, 4); p += __shfl_xor(p, 8);
            if (l15 == 0)
                slds[wn * 128 + wm * 64 + mi * 16 + lg * 4 + j] = p;
        }
    }
    __syncthreads();
    if (tid < 128)
        partial[(size_t)nb * (B * S) + mt * 128 + tid] = slds[tid] + slds[128 + tid];
}

// ---------------- softmax over S per batch (sums nparts N-partials) ------
__global__ __launch_bounds__(256) void softmax_kernel(
    const float* __restrict__ partial, float* __restrict__ attn, int nparts)
{
    const int b = blockIdx.x, tid = threadIdx.x;
    float xv[8];
    float m = -1e30f;
    #pragma unroll
    for (int i = 0; i < 8; ++i) {
        float s = 0.f;
        for (int nb = 0; nb < nparts; ++nb)
            s += partial[(size_t)nb * (B * S) + b * S + tid + i * 256];
        xv[i] = s;
        m = fmaxf(m, s);
    }
    #pragma unroll
    for (int off = 32; off; off >>= 1) m = fmaxf(m, __shfl_xor(m, off));
    __shared__ float wred[4], wsum[4];
    const int w = tid >> 6;
    if ((tid & 63) == 0) wred[w] = m;
    __syncthreads();
    const float M = fmaxf(fmaxf(wred[0], wred[1]), fmaxf(wred[2], wred[3]));
    float s = 0.f;
    #pragma unroll
    for (int i = 0; i < 8; ++i) { xv[i] = expf(xv[i] - M); s += xv[i]; }
    #pragma unroll
    for (int off = 32; off; off >>= 1) s += __shfl_xor(s, off);
    if ((tid & 63) == 0) wsum[w] = s;
    __syncthreads();
    const float inv = 1.f / (wsum[0] + wsum[1] + wsum[2] + wsum[3]);
    #pragma unroll
    for (int i = 0; i < 8; ++i) attn[b * S + tid + i * 256] = xv[i] * inv;
}

// ---------------- context: partial over S-chunks, then reduce ------------
__global__ __launch_bounds__(256) void ctx_partial(
    const float* __restrict__ enc, const float* __restrict__ attn,
    float* __restrict__ part, int rows)
{
    const int sc = blockIdx.x;
    const int b  = blockIdx.y;
    const int tid = threadIdx.x;
    const float* encb = enc + ((size_t)b * S + (size_t)sc * rows) * H;
    const float* wb = attn + b * S + sc * rows;
    __shared__ float wl[256];
    if (tid < rows) wl[tid] = wb[tid];
    __syncthreads();
    float4 acc = {0.f, 0.f, 0.f, 0.f};
    for (int s = 0; s < rows; ++s) {
        const float wgt = wl[s];
        const float4 e = *(const float4*)(encb + (size_t)s * H + tid * 4);
        acc.x += wgt * e.x; acc.y += wgt * e.y; acc.z += wgt * e.z; acc.w += wgt * e.w;
    }
    ((float4*)(part + ((size_t)(sc * B + b)) * H))[tid] = acc;
}

__global__ __launch_bounds__(256) void ctx_reduce(
    const float* __restrict__ part, float* __restrict__ ctx, int nch)
{
    const int i = blockIdx.x * 256 + threadIdx.x;
    float s = 0.f;
    for (int c = 0; c < nch; ++c) s += part[(size_t)c * (B * H) + i];
    ctx[i] = s;
}

extern "C" void kernel_launch(void* const* d_in, const int* in_sizes, int n_in,
                              void* d_out, int out_size, void* d_ws, size_t ws_size,
                              hipStream_t stream) {
    const float* hidden = (const float*)d_in[0];
    const float* enc    = (const float*)d_in[1];
    const float* W      = (const float*)d_in[2];
    const float* b_attn = (const float*)d_in[3];
    const float* v      = (const float*)d_in[4];
    float* ctx  = (float*)d_out;               // (B, H)
    float* attn = ctx + B * H;                 // (B, S)
    float* ws      = (float*)d_ws;
    float* region  = ws;                       // 524288 f32: score partials, then ctx part
    float* ph      = ws + 524288;              // 32768 f32
    _Float16* We_h = (_Float16*)(ws + 524288 + 32768);  // 1M halfs

    proj_h_kernel<<<dim3(H / 4, B), 256, 0, stream>>>(hidden, W, b_attn, ph);

    const size_t need_primary = (size_t)(524288 + 32768 + 524288) * 4;
    if (ws_size >= need_primary) {
        conv_We<<<1024, 256, 0, stream>>>(W, We_h);
        score_v12<<<2048, 512, 0, stream>>>(enc, We_h, ph, v, region);
        softmax_kernel<<<dim3(B), 256, 0, stream>>>(region, attn, 4);
    } else {
        score_v4f<<<4096, 256, 0, stream>>>(enc, W, ph, v, region);
        softmax_kernel<<<dim3(B), 256, 0, stream>>>(region, attn, 8);
    }
    ctx_partial<<<dim3(16, B), 256, 0, stream>>>(enc, attn, region, 128);
    ctx_reduce<<<dim3((B * H) / 256), 256, 0, stream>>>(region, ctx, 16);
}